// Round 1
// baseline (320.558 us; speedup 1.0000x reference)
//
#include <hip/hip_runtime.h>
#include <cstdint>
#include <cstddef>

// Problem constants
#define BB 64
#define TN 4096
#define FF 128
#define SPLIT 8                 // T-chunks per batch -> 512 blocks, 2/CU
#define CHUNK (TN / SPLIT)      // 512
#define TILE_T 32

// d_ws layout (in floats)
#define S2_OFF   0
#define S2_SZ    (BB * FF * FF)            // 1,048,576 floats (4 MiB)
#define SUM0_OFF (S2_OFF + S2_SZ)          // per (b,f) sum of x
#define MEAN_OFF (SUM0_OFF + BB * FF)
#define RSTD_OFF (MEAN_OFF + BB * FF)
#define SABS_OFF (RSTD_OFF + BB * FF)      // scalar: sum |x|
#define TRI_OFF  (SABS_OFF + 1)            // scalar: masked corr sum
#define WS_FLOATS (TRI_OFF + 1)

// ---------------------------------------------------------------------------
// Kernel 1: fused one-pass. For each (batch, T-chunk):
//   - stream x through LDS tile [32][128]
//   - accumulate per-thread 8x8 block of S2 = sum_t x_f x_g  (register tiling)
//   - accumulate per-column sum(x) and global sum|x|
// Partial results accumulated into d_ws via atomicAdd.
// ---------------------------------------------------------------------------
__global__ __launch_bounds__(256, 2) void cov_kernel(const float* __restrict__ x,
                                                     float* __restrict__ ws)
{
    __shared__ float tile[TILE_T][FF];    // 16 KiB
    __shared__ float redsa[4];

    const int b = blockIdx.x / SPLIT;
    const int s = blockIdx.x % SPLIT;
    const float* xb = x + ((size_t)b * TN + (size_t)s * CHUNK) * FF;

    const int tid  = threadIdx.x;
    const int c4   = tid & 31;   // float4 column (0..31)
    const int rowo = tid >> 5;   // row offset (0..7)
    const int ty   = tid >> 4;   // 0..15 -> output rows  8*ty..8*ty+7
    const int tx   = tid & 15;   // 0..15 -> output cols  8*tx..8*tx+7

    float acc[8][8];
#pragma unroll
    for (int i = 0; i < 8; ++i)
#pragma unroll
        for (int j = 0; j < 8; ++j) acc[i][j] = 0.f;

    float s0[4] = {0.f, 0.f, 0.f, 0.f};
    float sa = 0.f;

    for (int t0 = 0; t0 < CHUNK; t0 += TILE_T) {
        // ---- stage 32 rows x 128 cols, float4-coalesced ----
#pragma unroll
        for (int k = 0; k < TILE_T / 8; ++k) {
            const int r = k * 8 + rowo;
            float4 v = *(const float4*)(xb + (size_t)(t0 + r) * FF + (c4 << 2));
            s0[0] += v.x; s0[1] += v.y; s0[2] += v.z; s0[3] += v.w;
            sa += fabsf(v.x) + fabsf(v.y) + fabsf(v.z) + fabsf(v.w);
            *(float4*)&tile[r][c4 << 2] = v;
        }
        __syncthreads();

        // ---- rank-32 update of the 8x8 register tile ----
#pragma unroll 2
        for (int t = 0; t < TILE_T; ++t) {
            float a[8], bv[8];
            *(float4*)&a[0]  = *(const float4*)&tile[t][ty * 8];
            *(float4*)&a[4]  = *(const float4*)&tile[t][ty * 8 + 4];
            *(float4*)&bv[0] = *(const float4*)&tile[t][tx * 8];
            *(float4*)&bv[4] = *(const float4*)&tile[t][tx * 8 + 4];
#pragma unroll
            for (int i = 0; i < 8; ++i)
#pragma unroll
                for (int j = 0; j < 8; ++j)
                    acc[i][j] = fmaf(a[i], bv[j], acc[i][j]);
        }
        __syncthreads();
    }

    // ---- accumulate S2 partials ----
    float* S2b = ws + S2_OFF + (size_t)b * FF * FF;
#pragma unroll
    for (int i = 0; i < 8; ++i)
#pragma unroll
        for (int j = 0; j < 8; ++j)
            atomicAdd(&S2b[(ty * 8 + i) * FF + tx * 8 + j], acc[i][j]);

    // ---- reduce per-column sums (8 threads share each float4 column) ----
    float* sc = &tile[0][0];   // tile no longer needed (synced above)
#pragma unroll
    for (int q = 0; q < 4; ++q)
        sc[rowo * FF + (c4 << 2) + q] = s0[q];
    __syncthreads();
    if (tid < FF) {
        float tot = 0.f;
#pragma unroll
        for (int r = 0; r < 8; ++r) tot += sc[r * FF + tid];
        atomicAdd(&ws[SUM0_OFF + b * FF + tid], tot);
    }

    // ---- reduce sum|x| ----
#pragma unroll
    for (int off = 32; off > 0; off >>= 1) sa += __shfl_down(sa, off, 64);
    const int lane = tid & 63, wid = tid >> 6;
    if (lane == 0) redsa[wid] = sa;
    __syncthreads();
    if (tid == 0)
        atomicAdd(&ws[SABS_OFF], redsa[0] + redsa[1] + redsa[2] + redsa[3]);
}

// ---------------------------------------------------------------------------
// Kernel 2: per (b,f) mean and 1/std from S2 diagonal. 8192 threads.
// ---------------------------------------------------------------------------
__global__ void stats_kernel(float* __restrict__ ws)
{
    const int idx = blockIdx.x * blockDim.x + threadIdx.x;  // 0..8191
    const int b = idx >> 7, f = idx & 127;
    const float mean = ws[SUM0_OFF + idx] * (1.f / TN);
    const float var =
        ws[S2_OFF + (size_t)b * FF * FF + f * FF + f] * (1.f / TN) - mean * mean;
    ws[MEAN_OFF + idx] = mean;
    ws[RSTD_OFF + idx] = rsqrtf(fmaxf(var, 1e-30f));
}

// ---------------------------------------------------------------------------
// Kernel 3: corr_avg_abs + strict-upper-triangular masked sum.
// One thread per (f,g) pair; loop over batches (coalesced over g).
// ---------------------------------------------------------------------------
__global__ __launch_bounds__(256) void corr_kernel(float* __restrict__ ws)
{
    __shared__ float red[4];
    const int p = blockIdx.x * 256 + threadIdx.x;   // 0..16383
    const int f = p >> 7, g = p & 127;

    float accum = 0.f;
    for (int b = 0; b < BB; ++b) {
        const float s2 = ws[S2_OFF + (size_t)b * FF * FF + p];
        const float mf = ws[MEAN_OFF + b * FF + f];
        const float mg = ws[MEAN_OFF + b * FF + g];
        const float rf = ws[RSTD_OFF + b * FF + f];
        const float rg = ws[RSTD_OFF + b * FF + g];
        accum += (s2 * (1.f / TN) - mf * mg) * rf * rg;
    }
    float v = (g > f) ? fabsf(accum * (1.f / BB)) : 0.f;

#pragma unroll
    for (int off = 32; off > 0; off >>= 1) v += __shfl_down(v, off, 64);
    const int lane = threadIdx.x & 63, wid = threadIdx.x >> 6;
    if (lane == 0) red[wid] = v;
    __syncthreads();
    if (threadIdx.x == 0)
        atomicAdd(&ws[TRI_OFF], red[0] + red[1] + red[2] + red[3]);
}

// ---------------------------------------------------------------------------
// Kernel 4: write the 3 outputs.
// ---------------------------------------------------------------------------
__global__ void final_kernel(const float* __restrict__ ws, float* __restrict__ out)
{
    const float tri  = ws[TRI_OFF];
    const float sabs = ws[SABS_OFF];
    const float n_pairs = (float)(FF * (FF - 1) / 2);   // 8128
    out[0] = tri * (0.01f / n_pairs);
    out[1] = tri;
    out[2] = sabs * (1.f / FF);
}

extern "C" void kernel_launch(void* const* d_in, const int* in_sizes, int n_in,
                              void* d_out, int out_size, void* d_ws, size_t ws_size,
                              hipStream_t stream)
{
    const float* x = (const float*)d_in[0];
    float* out = (float*)d_out;
    float* ws = (float*)d_ws;

    // zero the accumulation regions of the workspace every call
    hipMemsetAsync(d_ws, 0, (size_t)WS_FLOATS * sizeof(float), stream);

    hipLaunchKernelGGL(cov_kernel,  dim3(BB * SPLIT), dim3(256), 0, stream, x, ws);
    hipLaunchKernelGGL(stats_kernel, dim3((BB * FF) / 256), dim3(256), 0, stream, ws);
    hipLaunchKernelGGL(corr_kernel, dim3((FF * FF) / 256), dim3(256), 0, stream, ws);
    hipLaunchKernelGGL(final_kernel, dim3(1), dim3(1), 0, stream, ws, out);
}

// Round 2
// 87.779 us; speedup vs baseline: 3.6519x; 3.6519x over previous
//
#include <hip/hip_runtime.h>
#include <cstdint>
#include <cstddef>

// Problem constants
#define BB 64
#define TN 4096
#define FF 128
#define SPLIT 8                  // chunks per batch -> 512 blocks, 2/CU
#define CHUNK (TN / SPLIT)       // 512
#define KT 64                    // t-rows per LDS tile
#define NKT (CHUNK / KT)         // 8
#define LDS_STRIDE 72            // bytes per f-row: 64 data + 8 pad (8B-aligned reads, spread banks)

// d_ws layout (floats)
#define S2_OFF   0
#define S2_SZ    (BB * FF * FF)
#define SUM0_OFF (S2_OFF + S2_SZ)
#define MEAN_OFF (SUM0_OFF + BB * FF)
#define RSTD_OFF (MEAN_OFF + BB * FF)
#define SABS_OFF (RSTD_OFF + BB * FF)
#define TRI_OFF  (SABS_OFF + 1)
#define WS_FLOATS (TRI_OFF + 1)

typedef __attribute__((ext_vector_type(8))) short bf16x8_t;
typedef __attribute__((ext_vector_type(4))) short short4_t;
typedef __attribute__((ext_vector_type(4))) float f32x4;

static __device__ __forceinline__ unsigned f2bf(float f) {
    unsigned u = __builtin_bit_cast(unsigned, f);
    return (u + 0x7FFFu + ((u >> 16) & 1u)) >> 16;   // RNE
}

// ---------------------------------------------------------------------------
// Kernel 1: bf16-MFMA syrk (upper triangle) + fused column sums + sum|x|.
// Each block: one (batch, 512-row chunk). 256 threads = 4 waves.
// Wave w computes row-strips {w, w+4} (16 rows each) x all needed col-tiles.
// LDS holds X^T [f][k] bf16, double-buffered.
// ---------------------------------------------------------------------------
__global__ __launch_bounds__(256, 2) void cov_kernel(const float* __restrict__ x,
                                                     float* __restrict__ ws)
{
    __shared__ __align__(16) char lds[2][FF * LDS_STRIDE];   // 2 x 9216 B

    const int b = blockIdx.x / SPLIT;
    const int s = blockIdx.x % SPLIT;
    const float* xb = x + ((size_t)b * TN + (size_t)s * CHUNK) * FF;

    const int tid = threadIdx.x;
    // staging coords: thread owns a 4t x 4f micro-tile per 32-row step
    const int c = tid & 31;        // f-quad: f = 4c..4c+3
    const int r = tid >> 3 >> 2;   // == tid >> 5, 0..7: t-base = 4r within step
    // fragment coords
    const int w    = tid >> 6;     // wave 0..3
    const int lane = tid & 63;
    const int m    = lane & 15;
    const int h    = lane >> 4;    // 0..3

    f32x4 acc0[8], acc1[4];
#pragma unroll
    for (int i = 0; i < 8; ++i) acc0[i] = (f32x4){0.f, 0.f, 0.f, 0.f};
#pragma unroll
    for (int i = 0; i < 4; ++i) acc1[i] = (f32x4){0.f, 0.f, 0.f, 0.f};

    float csum[4] = {0.f, 0.f, 0.f, 0.f};
    float sa = 0.f;

    float4 ld[2][4];   // 2 steps x 4 rows, in-flight staging registers

    auto issue_loads = [&](int kt) {
        const float* g = xb + (size_t)kt * KT * FF + c * 4;
#pragma unroll
        for (int st = 0; st < 2; ++st)
#pragma unroll
            for (int i = 0; i < 4; ++i)
                ld[st][i] = *(const float4*)(g + (size_t)(st * 32 + r * 4 + i) * FF);
    };

    auto pack_write = [&](char* buf) {
#pragma unroll
        for (int st = 0; st < 2; ++st) {
            const int t0 = st * 32 + r * 4;
            float rowv[4][4];
#pragma unroll
            for (int i = 0; i < 4; ++i) {
                rowv[i][0] = ld[st][i].x; rowv[i][1] = ld[st][i].y;
                rowv[i][2] = ld[st][i].z; rowv[i][3] = ld[st][i].w;
            }
#pragma unroll
            for (int j = 0; j < 4; ++j) {
                const float v0 = rowv[0][j], v1 = rowv[1][j];
                const float v2 = rowv[2][j], v3 = rowv[3][j];
                csum[j] += (v0 + v1) + (v2 + v3);
                sa += (fabsf(v0) + fabsf(v1)) + (fabsf(v2) + fabsf(v3));
                uint2 val;
                val.x = f2bf(v0) | (f2bf(v1) << 16);
                val.y = f2bf(v2) | (f2bf(v3) << 16);
                *(uint2*)(buf + (c * 4 + j) * LDS_STRIDE + t0 * 2) = val;
            }
        }
    };

    auto read_frag = [&](const char* buf, int ft, int koff) -> bf16x8_t {
        const char* p = buf + (ft * 16 + m) * LDS_STRIDE + koff;
        short4_t lo = *(const short4_t*)p;
        short4_t hi = *(const short4_t*)(p + 8);
        return (bf16x8_t){lo.x, lo.y, lo.z, lo.w, hi.x, hi.y, hi.z, hi.w};
    };

    auto compute = [&](const char* buf) {
#pragma unroll
        for (int kk = 0; kk < 2; ++kk) {
            const int koff = kk * 64 + h * 16;
            bf16x8_t a0 = read_frag(buf, w, koff);
            bf16x8_t a1 = read_frag(buf, w + 4, koff);
            bf16x8_t bfr[8];
#pragma unroll
            for (int n = 0; n < 8; ++n) bfr[n] = read_frag(buf, n, koff);
#pragma unroll
            for (int n = 0; n < 8; ++n)
                acc0[n] = __builtin_amdgcn_mfma_f32_16x16x32_bf16(a0, bfr[n], acc0[n], 0, 0, 0);
#pragma unroll
            for (int n = 0; n < 4; ++n)
                acc1[n] = __builtin_amdgcn_mfma_f32_16x16x32_bf16(a1, bfr[n + 4], acc1[n], 0, 0, 0);
        }
    };

    // prologue: stage tile 0
    issue_loads(0);
    pack_write(&lds[0][0]);
    __syncthreads();

    for (int kt = 0; kt < NKT; ++kt) {
        if (kt + 1 < NKT) issue_loads(kt + 1);         // hide HBM under MFMA
        compute(&lds[kt & 1][0]);
        if (kt + 1 < NKT) pack_write(&lds[(kt + 1) & 1][0]);
        __syncthreads();
    }

    // ---- epilogue: atomically accumulate upper-triangular tiles ----
    float* S2b = ws + S2_OFF + (size_t)b * FF * FF;
#pragma unroll
    for (int n = 0; n < 8; ++n) {
        if (n >= w) {
#pragma unroll
            for (int q = 0; q < 4; ++q) {
                const int row = w * 16 + h * 4 + q;     // C/D: row=(lane>>4)*4+reg
                const int col = n * 16 + m;             //      col=lane&15
                atomicAdd(&S2b[row * FF + col], acc0[n][q]);
            }
        }
    }
#pragma unroll
    for (int n4 = 0; n4 < 4; ++n4) {
        if (n4 >= w) {
#pragma unroll
            for (int q = 0; q < 4; ++q) {
                const int row = (w + 4) * 16 + h * 4 + q;
                const int col = (n4 + 4) * 16 + m;
                atomicAdd(&S2b[row * FF + col], acc1[n4][q]);
            }
        }
    }

    // ---- column sums (fp32, from staged registers) ----
#pragma unroll
    for (int j = 0; j < 4; ++j)
        atomicAdd(&ws[SUM0_OFF + b * FF + c * 4 + j], csum[j]);

    // ---- sum |x| ----
#pragma unroll
    for (int off = 32; off > 0; off >>= 1) sa += __shfl_down(sa, off, 64);
    if (lane == 0) atomicAdd(&ws[SABS_OFF], sa);
}

// ---------------------------------------------------------------------------
// Kernel 2: per (b,f) mean and 1/std from S2 diagonal.
// ---------------------------------------------------------------------------
__global__ void stats_kernel(float* __restrict__ ws)
{
    const int idx = blockIdx.x * blockDim.x + threadIdx.x;  // 0..8191
    const int b = idx >> 7, f = idx & 127;
    const float mean = ws[SUM0_OFF + idx] * (1.f / TN);
    const float var =
        ws[S2_OFF + (size_t)b * FF * FF + f * FF + f] * (1.f / TN) - mean * mean;
    ws[MEAN_OFF + idx] = mean;
    ws[RSTD_OFF + idx] = rsqrtf(fmaxf(var, 1e-30f));
}

// ---------------------------------------------------------------------------
// Kernel 3: corr_avg_abs + strict upper-tri masked sum (upper tiles only).
// ---------------------------------------------------------------------------
__global__ __launch_bounds__(256) void corr_kernel(float* __restrict__ ws)
{
    __shared__ float red[4];
    const int p = blockIdx.x * 256 + threadIdx.x;   // 0..16383
    const int f = p >> 7, g = p & 127;

    float accum = 0.f;
    for (int b = 0; b < BB; ++b) {
        const float s2 = ws[S2_OFF + (size_t)b * FF * FF + p];
        const float mf = ws[MEAN_OFF + b * FF + f];
        const float mg = ws[MEAN_OFF + b * FF + g];
        const float rf = ws[RSTD_OFF + b * FF + f];
        const float rg = ws[RSTD_OFF + b * FF + g];
        accum += (s2 * (1.f / TN) - mf * mg) * rf * rg;
    }
    float v = (g > f) ? fabsf(accum * (1.f / BB)) : 0.f;

#pragma unroll
    for (int off = 32; off > 0; off >>= 1) v += __shfl_down(v, off, 64);
    const int lane = threadIdx.x & 63, wid = threadIdx.x >> 6;
    if (lane == 0) red[wid] = v;
    __syncthreads();
    if (threadIdx.x == 0)
        atomicAdd(&ws[TRI_OFF], red[0] + red[1] + red[2] + red[3]);
}

// ---------------------------------------------------------------------------
// Kernel 4: write the 3 outputs.
// ---------------------------------------------------------------------------
__global__ void final_kernel(const float* __restrict__ ws, float* __restrict__ out)
{
    const float tri  = ws[TRI_OFF];
    const float sabs = ws[SABS_OFF];
    const float n_pairs = (float)(FF * (FF - 1) / 2);   // 8128
    out[0] = tri * (0.01f / n_pairs);
    out[1] = tri;
    out[2] = sabs * (1.f / FF);
}

extern "C" void kernel_launch(void* const* d_in, const int* in_sizes, int n_in,
                              void* d_out, int out_size, void* d_ws, size_t ws_size,
                              hipStream_t stream)
{
    const float* x = (const float*)d_in[0];
    float* out = (float*)d_out;
    float* ws = (float*)d_ws;

    hipMemsetAsync(d_ws, 0, (size_t)WS_FLOATS * sizeof(float), stream);

    hipLaunchKernelGGL(cov_kernel,  dim3(BB * SPLIT), dim3(256), 0, stream, x, ws);
    hipLaunchKernelGGL(stats_kernel, dim3((BB * FF) / 256), dim3(256), 0, stream, ws);
    hipLaunchKernelGGL(corr_kernel, dim3((FF * FF) / 256), dim3(256), 0, stream, ws);
    hipLaunchKernelGGL(final_kernel, dim3(1), dim3(1), 0, stream, ws, out);
}

// Round 3
// 84.989 us; speedup vs baseline: 3.7718x; 1.0328x over previous
//
#include <hip/hip_runtime.h>
#include <cstdint>
#include <cstddef>

// Problem constants
#define BB 64
#define TN 4096
#define FF 128
#define SPLIT 8                  // chunks per batch -> 512 blocks, 2/CU
#define NBLK (BB * SPLIT)        // 512
#define CHUNK (TN / SPLIT)       // 512
#define KT 64                    // t-rows per LDS tile
#define NKT (CHUNK / KT)         // 8
#define LDS_STRIDE 72            // bytes per f-row: 64 data + 8 pad

#define NTILE_UP 36              // upper-triangular 16x16 tiles of 128x128
#define TILE_ELEMS 256
#define PART_FLOATS (NTILE_UP * TILE_ELEMS)   // 9216 per block partial

// d_ws layout (floats): small atomic region first (memset'd), then big arrays
#define SUM0_OFF 0
#define MEAN_OFF (SUM0_OFF + BB * FF)
#define RSTD_OFF (MEAN_OFF + BB * FF)
#define SABS_OFF (RSTD_OFF + BB * FF)
#define TRI_OFF  (SABS_OFF + 1)
#define ZERO_FLOATS (TRI_OFF + 1)
#define R_OFF    24832                        // reduced S2 tiles: [BB][9216]
#define P_OFF    (R_OFF + BB * PART_FLOATS)   // partials: [NBLK][9216]
// total = 24832 + 589824 + 4718592 floats ~= 21.3 MB

typedef __attribute__((ext_vector_type(8))) short bf16x8_t;
typedef __attribute__((ext_vector_type(4))) short short4_t;
typedef __attribute__((ext_vector_type(4))) float f32x4;

__device__ __constant__ int kRowBase[8] = {0, 8, 15, 21, 26, 30, 33, 35};

static __device__ __forceinline__ unsigned f2bf(float f) {
    unsigned u = __builtin_bit_cast(unsigned, f);
    return (u + 0x7FFFu + ((u >> 16) & 1u)) >> 16;   // RNE
}

// ---------------------------------------------------------------------------
// Kernel 1: bf16-MFMA syrk (upper triangle) + fused column sums + sum|x|.
// Per-block partial S2 tiles stored compactly (NO atomics).
// ---------------------------------------------------------------------------
__global__ __launch_bounds__(256, 2) void cov_kernel(const float* __restrict__ x,
                                                     float* __restrict__ ws)
{
    __shared__ __align__(16) char lds[2][FF * LDS_STRIDE];   // 2 x 9216 B

    const int b = blockIdx.x / SPLIT;
    const int s = blockIdx.x % SPLIT;
    const float* xb = x + ((size_t)b * TN + (size_t)s * CHUNK) * FF;

    const int tid = threadIdx.x;
    const int c = tid & 31;        // f-quad: f = 4c..4c+3
    const int r = tid >> 5;        // 0..7: t-base = 4r within 32-row step
    const int w    = tid >> 6;     // wave 0..3
    const int lane = tid & 63;
    const int m    = lane & 15;
    const int h    = lane >> 4;    // 0..3

    f32x4 acc0[8], acc1[4];
#pragma unroll
    for (int i = 0; i < 8; ++i) acc0[i] = (f32x4){0.f, 0.f, 0.f, 0.f};
#pragma unroll
    for (int i = 0; i < 4; ++i) acc1[i] = (f32x4){0.f, 0.f, 0.f, 0.f};

    float csum[4] = {0.f, 0.f, 0.f, 0.f};
    float sa = 0.f;

    float4 ld[2][4];

    auto issue_loads = [&](int kt) {
        const float* g = xb + (size_t)kt * KT * FF + c * 4;
#pragma unroll
        for (int st = 0; st < 2; ++st)
#pragma unroll
            for (int i = 0; i < 4; ++i)
                ld[st][i] = *(const float4*)(g + (size_t)(st * 32 + r * 4 + i) * FF);
    };

    auto pack_write = [&](char* buf) {
#pragma unroll
        for (int st = 0; st < 2; ++st) {
            const int t0 = st * 32 + r * 4;
            float rowv[4][4];
#pragma unroll
            for (int i = 0; i < 4; ++i) {
                rowv[i][0] = ld[st][i].x; rowv[i][1] = ld[st][i].y;
                rowv[i][2] = ld[st][i].z; rowv[i][3] = ld[st][i].w;
            }
#pragma unroll
            for (int j = 0; j < 4; ++j) {
                const float v0 = rowv[0][j], v1 = rowv[1][j];
                const float v2 = rowv[2][j], v3 = rowv[3][j];
                csum[j] += (v0 + v1) + (v2 + v3);
                sa += (fabsf(v0) + fabsf(v1)) + (fabsf(v2) + fabsf(v3));
                uint2 val;
                val.x = f2bf(v0) | (f2bf(v1) << 16);
                val.y = f2bf(v2) | (f2bf(v3) << 16);
                *(uint2*)(buf + (c * 4 + j) * LDS_STRIDE + t0 * 2) = val;
            }
        }
    };

    auto read_frag = [&](const char* buf, int ft, int koff) -> bf16x8_t {
        const char* p = buf + (ft * 16 + m) * LDS_STRIDE + koff;
        short4_t lo = *(const short4_t*)p;
        short4_t hi = *(const short4_t*)(p + 8);
        return (bf16x8_t){lo.x, lo.y, lo.z, lo.w, hi.x, hi.y, hi.z, hi.w};
    };

    auto compute = [&](const char* buf) {
#pragma unroll
        for (int kk = 0; kk < 2; ++kk) {
            const int koff = kk * 64 + h * 16;
            bf16x8_t a0 = read_frag(buf, w, koff);
            bf16x8_t a1 = read_frag(buf, w + 4, koff);
            bf16x8_t bfr[8];
#pragma unroll
            for (int n = 0; n < 8; ++n) bfr[n] = read_frag(buf, n, koff);
#pragma unroll
            for (int n = 0; n < 8; ++n)
                acc0[n] = __builtin_amdgcn_mfma_f32_16x16x32_bf16(a0, bfr[n], acc0[n], 0, 0, 0);
#pragma unroll
            for (int n = 0; n < 4; ++n)
                acc1[n] = __builtin_amdgcn_mfma_f32_16x16x32_bf16(a1, bfr[n + 4], acc1[n], 0, 0, 0);
        }
    };

    issue_loads(0);
    pack_write(&lds[0][0]);
    __syncthreads();

    for (int kt = 0; kt < NKT; ++kt) {
        if (kt + 1 < NKT) issue_loads(kt + 1);
        compute(&lds[kt & 1][0]);
        if (kt + 1 < NKT) pack_write(&lds[(kt + 1) & 1][0]);
        __syncthreads();
    }

    // ---- epilogue: plain stores of upper-tri tile partials (no atomics) ----
    float* Pb = ws + P_OFF + (size_t)blockIdx.x * PART_FLOATS;
#pragma unroll
    for (int n = 0; n < 8; ++n) {
        if (n >= w) {
            const int tidx = kRowBase[w] + (n - w);
#pragma unroll
            for (int q = 0; q < 4; ++q)
                Pb[tidx * TILE_ELEMS + (h * 4 + q) * 16 + m] = acc0[n][q];
        }
    }
#pragma unroll
    for (int n4 = 0; n4 < 4; ++n4) {
        if (n4 >= w) {
            const int tidx = kRowBase[w + 4] + (n4 - w);
#pragma unroll
            for (int q = 0; q < 4; ++q)
                Pb[tidx * TILE_ELEMS + (h * 4 + q) * 16 + m] = acc1[n4][q];
        }
    }

    // ---- column sums (small atomics, 65K total) ----
#pragma unroll
    for (int j = 0; j < 4; ++j)
        atomicAdd(&ws[SUM0_OFF + b * FF + c * 4 + j], csum[j]);

    // ---- sum |x| ----
#pragma unroll
    for (int off = 32; off > 0; off >>= 1) sa += __shfl_down(sa, off, 64);
    if (lane == 0) atomicAdd(&ws[SABS_OFF], sa);
}

// ---------------------------------------------------------------------------
// Kernel 2: reduce the SPLIT per-chunk partials: R[b][e] = sum_s P[b*8+s][e]
// ---------------------------------------------------------------------------
__global__ __launch_bounds__(256) void reduce_kernel(float* __restrict__ ws)
{
    const int bb = blockIdx.x / NTILE_UP;                 // batch
    const int e  = (blockIdx.x % NTILE_UP) * 256 + threadIdx.x;
    const float* P = ws + P_OFF + (size_t)bb * SPLIT * PART_FLOATS + e;
    float acc = 0.f;
#pragma unroll
    for (int s = 0; s < SPLIT; ++s) acc += P[(size_t)s * PART_FLOATS];
    ws[R_OFF + (size_t)bb * PART_FLOATS + e] = acc;
}

// ---------------------------------------------------------------------------
// Kernel 3: per (b,f) mean and 1/std from S2 diagonal tiles.
// ---------------------------------------------------------------------------
__global__ void stats_kernel(float* __restrict__ ws)
{
    const int idx = blockIdx.x * blockDim.x + threadIdx.x;  // 0..8191
    const int b = idx >> 7, f = idx & 127;
    const float mean = ws[SUM0_OFF + idx] * (1.f / TN);
    const int tile = kRowBase[f >> 4];                      // diagonal tile
    const float s2d = ws[R_OFF + (size_t)b * PART_FLOATS + tile * TILE_ELEMS + (f & 15) * 17];
    const float var = s2d * (1.f / TN) - mean * mean;
    ws[MEAN_OFF + idx] = mean;
    ws[RSTD_OFF + idx] = rsqrtf(fmaxf(var, 1e-30f));
}

// ---------------------------------------------------------------------------
// Kernel 4: corr_avg_abs + strict upper-tri masked sum.
// ---------------------------------------------------------------------------
__global__ __launch_bounds__(256) void corr_kernel(float* __restrict__ ws)
{
    __shared__ float red[4];
    const int p = blockIdx.x * 256 + threadIdx.x;   // 0..16383
    const int f = p >> 7, g = p & 127;

    float v = 0.f;
    if (g > f) {
        const int tidx = kRowBase[f >> 4] + ((g >> 4) - (f >> 4));
        const size_t off = (size_t)tidx * TILE_ELEMS + (f & 15) * 16 + (g & 15);
        float accum = 0.f;
        for (int b = 0; b < BB; ++b) {
            const float s2 = ws[R_OFF + (size_t)b * PART_FLOATS + off];
            const float mf = ws[MEAN_OFF + b * FF + f];
            const float mg = ws[MEAN_OFF + b * FF + g];
            const float rf = ws[RSTD_OFF + b * FF + f];
            const float rg = ws[RSTD_OFF + b * FF + g];
            accum += (s2 * (1.f / TN) - mf * mg) * rf * rg;
        }
        v = fabsf(accum * (1.f / BB));
    }

#pragma unroll
    for (int off = 32; off > 0; off >>= 1) v += __shfl_down(v, off, 64);
    const int lane = threadIdx.x & 63, wid = threadIdx.x >> 6;
    if (lane == 0) red[wid] = v;
    __syncthreads();
    if (threadIdx.x == 0)
        atomicAdd(&ws[TRI_OFF], red[0] + red[1] + red[2] + red[3]);
}

// ---------------------------------------------------------------------------
// Kernel 5: write the 3 outputs.
// ---------------------------------------------------------------------------
__global__ void final_kernel(const float* __restrict__ ws, float* __restrict__ out)
{
    const float tri  = ws[TRI_OFF];
    const float sabs = ws[SABS_OFF];
    const float n_pairs = (float)(FF * (FF - 1) / 2);   // 8128
    out[0] = tri * (0.01f / n_pairs);
    out[1] = tri;
    out[2] = sabs * (1.f / FF);
}

extern "C" void kernel_launch(void* const* d_in, const int* in_sizes, int n_in,
                              void* d_out, int out_size, void* d_ws, size_t ws_size,
                              hipStream_t stream)
{
    const float* x = (const float*)d_in[0];
    float* out = (float*)d_out;
    float* ws = (float*)d_ws;

    // zero only the atomic-accumulation region
    hipMemsetAsync(d_ws, 0, (size_t)ZERO_FLOATS * sizeof(float), stream);

    hipLaunchKernelGGL(cov_kernel,    dim3(NBLK), dim3(256), 0, stream, x, ws);
    hipLaunchKernelGGL(reduce_kernel, dim3(BB * NTILE_UP), dim3(256), 0, stream, ws);
    hipLaunchKernelGGL(stats_kernel,  dim3((BB * FF) / 256), dim3(256), 0, stream, ws);
    hipLaunchKernelGGL(corr_kernel,   dim3((FF * FF) / 256), dim3(256), 0, stream, ws);
    hipLaunchKernelGGL(final_kernel,  dim3(1), dim3(1), 0, stream, ws, out);
}

// Round 4
// 66.180 us; speedup vs baseline: 4.8437x; 1.2842x over previous
//
#include <hip/hip_runtime.h>
#include <cstdint>
#include <cstddef>

// Problem constants
#define BB 64
#define TN 4096
#define FF 128
#define SPLIT 8                  // chunks per batch -> 512 blocks, 2/CU
#define NBLK (BB * SPLIT)        // 512
#define CHUNK (TN / SPLIT)       // 512
#define KT 32                    // t-rows per staged tile
#define NKT (CHUNK / KT)         // 16 phases
#define TSTRIDE 72               // bytes per f-row in bf16 transpose buffer

#define NTILE_UP 36              // upper-triangular 16x16 tiles of 128x128
#define TILE_ELEMS 256
#define PART_FLOATS (NTILE_UP * TILE_ELEMS)   // 9216 per block partial

// d_ws layout (floats): small atomic region first (memset'd), then big arrays
#define SUM0_OFF 0
#define MEAN_OFF (SUM0_OFF + BB * FF)
#define RSTD_OFF (MEAN_OFF + BB * FF)
#define SABS_OFF (RSTD_OFF + BB * FF)
#define TRI_OFF  (SABS_OFF + 1)
#define ZERO_FLOATS (TRI_OFF + 1)
#define R_OFF    24832                        // reduced S2 tiles: [BB][9216]
#define P_OFF    (R_OFF + BB * PART_FLOATS)   // partials: [NBLK][9216]

typedef __attribute__((ext_vector_type(8))) short bf16x8_t;
typedef __attribute__((ext_vector_type(4))) short short4_t;
typedef __attribute__((ext_vector_type(4))) float f32x4;

typedef const __attribute__((address_space(1))) uint32_t* gas_t;
typedef __attribute__((address_space(3))) uint32_t* las_t;

__device__ __constant__ int kRowBase[8] = {0, 8, 15, 21, 26, 30, 33, 35};

static __device__ __forceinline__ unsigned f2bf(float f) {
    unsigned u = __builtin_bit_cast(unsigned, f);
    return (u + 0x7FFFu + ((u >> 16) & 1u)) >> 16;   // RNE
}

// ---------------------------------------------------------------------------
// Kernel 1: async-staged bf16-MFMA syrk + fused column sums + sum|x|.
// Per phase p: stage(p+2 -> bufG[p&1]) via global_load_lds (no VGPR roundtrip);
//              transpose(p+1): bufG -> bf16 bufT[f][k] + csum/|x| accumulation;
//              mfma(p) from bufT; gate vmcnt(0)+lgkmcnt(0); raw s_barrier.
// ---------------------------------------------------------------------------
__global__ __launch_bounds__(256, 2) void cov_kernel(const float* __restrict__ x,
                                                     float* __restrict__ ws)
{
    __shared__ __align__(16) float bufG[2][KT * FF];       // 2 x 16 KiB fp32
    __shared__ __align__(16) char  bufT[2][FF * TSTRIDE];  // 2 x 9216 B bf16^T
    __shared__ float redsa[4];

    const int b = blockIdx.x / SPLIT;
    const int s = blockIdx.x % SPLIT;
    const float* xb = x + ((size_t)b * TN + (size_t)s * CHUNK) * FF;

    const int tid  = threadIdx.x;
    const int w    = tid >> 6;     // wave 0..3
    const int lane = tid & 63;
    const int m    = lane & 15;    // MFMA frag coords
    const int h    = lane >> 4;    // 0..3
    const int f    = tid & 127;    // transpose: owned feature column
    const int th   = tid >> 7;     // 0/1: t-halves 0..15 / 16..31

    f32x4 acc0[8], acc1[4];
#pragma unroll
    for (int i = 0; i < 8; ++i) acc0[i] = (f32x4){0.f, 0.f, 0.f, 0.f};
#pragma unroll
    for (int i = 0; i < 4; ++i) acc1[i] = (f32x4){0.f, 0.f, 0.f, 0.f};

    float csum = 0.f, sabs = 0.f;

    // wave w stages rows w*8 .. w*8+7 (4 instrs x 1 KiB, lane-linear dest)
    auto stage = [&](int kt) {
        if (kt >= NKT) return;
        const float* g = xb + ((size_t)kt * KT + w * 8) * FF + lane * 4;
        float* l = &bufG[kt & 1][w * 8 * FF];
#pragma unroll
        for (int i = 0; i < 4; ++i)
            __builtin_amdgcn_global_load_lds((gas_t)(g + i * 2 * FF),
                                             (las_t)(l + i * 2 * FF), 16, 0, 0);
    };

    // thread owns (column f, t-half th): 16 fp32 LDS reads -> bf16 packed writes
    auto transpose = [&](int kt) {
        if (kt >= NKT) return;
        const float* gb = &bufG[kt & 1][0];
        char* tb = &bufT[kt & 1][0];
        float v[16];
#pragma unroll
        for (int i = 0; i < 16; ++i) v[i] = gb[(th * 16 + i) * FF + f];
#pragma unroll
        for (int i = 0; i < 16; ++i) { csum += v[i]; sabs += fabsf(v[i]); }
#pragma unroll
        for (int q = 0; q < 4; ++q) {
            uint2 val;
            val.x = f2bf(v[q * 4 + 0]) | (f2bf(v[q * 4 + 1]) << 16);
            val.y = f2bf(v[q * 4 + 2]) | (f2bf(v[q * 4 + 3]) << 16);
            *(uint2*)(tb + f * TSTRIDE + th * 32 + q * 8) = val;
        }
    };

    auto read_frag = [&](const char* tb, int ft) -> bf16x8_t {
        const char* p = tb + (ft * 16 + m) * TSTRIDE + h * 16;
        short4_t lo = *(const short4_t*)p;
        short4_t hi = *(const short4_t*)(p + 8);
        return (bf16x8_t){lo.x, lo.y, lo.z, lo.w, hi.x, hi.y, hi.z, hi.w};
    };

    auto domfma = [&](int k) {
        const char* tb = &bufT[k & 1][0];
        bf16x8_t a0 = read_frag(tb, w);
        bf16x8_t a1 = read_frag(tb, w + 4);
        bf16x8_t bfr[8];
#pragma unroll
        for (int n = 0; n < 8; ++n) bfr[n] = read_frag(tb, n);
#pragma unroll
        for (int n = 0; n < 8; ++n)
            acc0[n] = __builtin_amdgcn_mfma_f32_16x16x32_bf16(a0, bfr[n], acc0[n], 0, 0, 0);
#pragma unroll
        for (int n = 0; n < 4; ++n)
            acc1[n] = __builtin_amdgcn_mfma_f32_16x16x32_bf16(a1, bfr[n + 4], acc1[n], 0, 0, 0);
    };

    // ---- prologue ----
    stage(0);
    stage(1);
    asm volatile("s_waitcnt vmcnt(4)" ::: "memory");       // tile 0 landed
    __builtin_amdgcn_s_barrier();
    __builtin_amdgcn_sched_barrier(0);
    transpose(0);
    asm volatile("s_waitcnt vmcnt(0) lgkmcnt(0)" ::: "memory");  // tile 1 landed, T0 visible
    __builtin_amdgcn_s_barrier();
    __builtin_amdgcn_sched_barrier(0);

    // ---- main pipeline: one barrier per phase, counted waits only ----
    for (int p = 0; p < NKT; ++p) {
        stage(p + 2);          // async into bufG[p&1] (no readers this phase)
        transpose(p + 1);      // bufG[(p+1)&1] -> bufT[(p+1)&1]
        domfma(p);             // bufT[p&1]
        asm volatile("s_waitcnt vmcnt(0) lgkmcnt(0)" ::: "memory");
        __builtin_amdgcn_s_barrier();
        __builtin_amdgcn_sched_barrier(0);
    }

    // ---- epilogue: plain stores of upper-tri tile partials ----
    float* Pb = ws + P_OFF + (size_t)blockIdx.x * PART_FLOATS;
#pragma unroll
    for (int n = 0; n < 8; ++n) {
        if (n >= w) {
            const int tidx = kRowBase[w] + (n - w);
#pragma unroll
            for (int q = 0; q < 4; ++q)
                Pb[tidx * TILE_ELEMS + (h * 4 + q) * 16 + m] = acc0[n][q];
        }
    }
#pragma unroll
    for (int n4 = 0; n4 < 4; ++n4) {
        if (n4 >= w) {
            const int tidx = kRowBase[w + 4] + (n4 - w);
#pragma unroll
            for (int q = 0; q < 4; ++q)
                Pb[tidx * TILE_ELEMS + (h * 4 + q) * 16 + m] = acc1[n4][q];
        }
    }

    // ---- column sums (two partial owners per f) ----
    atomicAdd(&ws[SUM0_OFF + b * FF + f], csum);

    // ---- sum |x| ----
#pragma unroll
    for (int off = 32; off > 0; off >>= 1) sabs += __shfl_down(sabs, off, 64);
    if (lane == 0) redsa[w] = sabs;
    __syncthreads();
    if (tid == 0)
        atomicAdd(&ws[SABS_OFF], redsa[0] + redsa[1] + redsa[2] + redsa[3]);
}

// ---------------------------------------------------------------------------
// Kernel 2: reduce the SPLIT per-chunk partials: R[b][e] = sum_s P[b*8+s][e]
// ---------------------------------------------------------------------------
__global__ __launch_bounds__(256) void reduce_kernel(float* __restrict__ ws)
{
    const int bb = blockIdx.x / NTILE_UP;                 // batch
    const int e  = (blockIdx.x % NTILE_UP) * 256 + threadIdx.x;
    const float* P = ws + P_OFF + (size_t)bb * SPLIT * PART_FLOATS + e;
    float acc = 0.f;
#pragma unroll
    for (int s = 0; s < SPLIT; ++s) acc += P[(size_t)s * PART_FLOATS];
    ws[R_OFF + (size_t)bb * PART_FLOATS + e] = acc;
}

// ---------------------------------------------------------------------------
// Kernel 3: per (b,f) mean and 1/std from S2 diagonal tiles.
// ---------------------------------------------------------------------------
__global__ void stats_kernel(float* __restrict__ ws)
{
    const int idx = blockIdx.x * blockDim.x + threadIdx.x;  // 0..8191
    const int b = idx >> 7, f = idx & 127;
    const float mean = ws[SUM0_OFF + idx] * (1.f / TN);
    const int tile = kRowBase[f >> 4];                      // diagonal tile
    const float s2d = ws[R_OFF + (size_t)b * PART_FLOATS + tile * TILE_ELEMS + (f & 15) * 17];
    const float var = s2d * (1.f / TN) - mean * mean;
    ws[MEAN_OFF + idx] = mean;
    ws[RSTD_OFF + idx] = rsqrtf(fmaxf(var, 1e-30f));
}

// ---------------------------------------------------------------------------
// Kernel 4: corr_avg_abs + strict upper-tri masked sum.
// ---------------------------------------------------------------------------
__global__ __launch_bounds__(256) void corr_kernel(float* __restrict__ ws)
{
    __shared__ float red[4];
    const int p = blockIdx.x * 256 + threadIdx.x;   // 0..16383
    const int f = p >> 7, g = p & 127;

    float v = 0.f;
    if (g > f) {
        const int tidx = kRowBase[f >> 4] + ((g >> 4) - (f >> 4));
        const size_t off = (size_t)tidx * TILE_ELEMS + (f & 15) * 16 + (g & 15);
        float accum = 0.f;
        for (int b = 0; b < BB; ++b) {
            const float s2 = ws[R_OFF + (size_t)b * PART_FLOATS + off];
            const float mf = ws[MEAN_OFF + b * FF + f];
            const float mg = ws[MEAN_OFF + b * FF + g];
            const float rf = ws[RSTD_OFF + b * FF + f];
            const float rg = ws[RSTD_OFF + b * FF + g];
            accum += (s2 * (1.f / TN) - mf * mg) * rf * rg;
        }
        v = fabsf(accum * (1.f / BB));
    }

#pragma unroll
    for (int off = 32; off > 0; off >>= 1) v += __shfl_down(v, off, 64);
    const int lane = threadIdx.x & 63, wid = threadIdx.x >> 6;
    if (lane == 0) red[wid] = v;
    __syncthreads();
    if (threadIdx.x == 0)
        atomicAdd(&ws[TRI_OFF], red[0] + red[1] + red[2] + red[3]);
}

// ---------------------------------------------------------------------------
// Kernel 5: write the 3 outputs.
// ---------------------------------------------------------------------------
__global__ void final_kernel(const float* __restrict__ ws, float* __restrict__ out)
{
    const float tri  = ws[TRI_OFF];
    const float sabs = ws[SABS_OFF];
    const float n_pairs = (float)(FF * (FF - 1) / 2);   // 8128
    out[0] = tri * (0.01f / n_pairs);
    out[1] = tri;
    out[2] = sabs * (1.f / FF);
}

extern "C" void kernel_launch(void* const* d_in, const int* in_sizes, int n_in,
                              void* d_out, int out_size, void* d_ws, size_t ws_size,
                              hipStream_t stream)
{
    const float* x = (const float*)d_in[0];
    float* out = (float*)d_out;
    float* ws = (float*)d_ws;

    // zero only the atomic-accumulation region
    hipMemsetAsync(d_ws, 0, (size_t)ZERO_FLOATS * sizeof(float), stream);

    hipLaunchKernelGGL(cov_kernel,    dim3(NBLK), dim3(256), 0, stream, x, ws);
    hipLaunchKernelGGL(reduce_kernel, dim3(BB * NTILE_UP), dim3(256), 0, stream, ws);
    hipLaunchKernelGGL(stats_kernel,  dim3((BB * FF) / 256), dim3(256), 0, stream, ws);
    hipLaunchKernelGGL(corr_kernel,   dim3((FF * FF) / 256), dim3(256), 0, stream, ws);
    hipLaunchKernelGGL(final_kernel,  dim3(1), dim3(1), 0, stream, ws, out);
}